// Round 8
// baseline (40808.655 us; speedup 1.0000x reference)
//
#include <hip/hip_runtime.h>
#include <cstdint>
#include <cstddef>

// B=256 batch, n=512 classes/steps, H=512 hidden, 3H=1536.
#define BB 256
#define NN 512
#define HH 512
#define G3 1536

typedef short bf16x8 __attribute__((ext_vector_type(8)));
typedef float f32x4 __attribute__((ext_vector_type(4)));

// ---------------- static device state ----------------
// Weight planes (hi then lo), MFMA fragment order. 1536-row weights use
// GATE-INTERLEAVED tiles: tile(c) = ((c&511)>>4)*3 + (c>>9)  (c = W row):
// tile u*3+g holds rows {g*512 + u*16 + i}. W_out: tile = c>>4.
// Fragment offset: (tile*16 + S)*512 + qu*128 + ci*8 + j   (S=k>>5 etc).
__device__ __align__(16) short g_Whh0[2 * 786432];
__device__ __align__(16) short g_Whh1[2 * 786432];
__device__ __align__(16) short g_Wih1[2 * 786432];
__device__ __align__(16) short g_Wout[2 * 262144];
// h-state bf16 hi/lo planes, double buffered by parity; A-fragment order:
// off(b,h) = (b>>4)*8192 + (h>>5)*512 + ((h>>3)&3)*128 + (b&15)*8 + (h&7)
__device__ __align__(16) short g_h0p[2][2 * 131072];
__device__ __align__(16) short g_h1p[2][2 * 131072];
__device__ __align__(16) float g_h0f[BB * HH];   // exact fp32 hold terms
__device__ __align__(16) float g_h1f[BB * HH];   // (same-thread-role RMW)
__device__ __align__(16) float g_gh1[BB * G3];   // [b][g*512+h], incl b_hh1
__device__ __align__(16) float g_logits[2][BB * NN];  // atomic partial sums
__device__ __align__(16) float g_gum[2][BB * NN];     // per-step gumbels
__device__ __align__(16) float g_WihT[NN * G3];  // W_ih0^T rows for gather
__device__ __align__(16) float g_ones[G3];       // gi0 at t=0 (incl b_ih0)
__device__ float g_lp[BB];
__device__ unsigned g_avail[2][BB * 16];
__device__ int g_idx[BB];
// Per-step, per-mt intra-kernel fence counters (fresh slot per t; no reuse).
__device__ int g_done[NN][16];

// ---------------- bf16 hi/lo helpers ----------------
__device__ __forceinline__ unsigned short bf16_rne(float f) {
  uint32_t u = __float_as_uint(f);
  uint32_t r = u + 0x7FFFu + ((u >> 16) & 1u);
  return (unsigned short)(r >> 16);
}
__device__ __forceinline__ float bf16_to_f(unsigned short h) {
  return __uint_as_float(((uint32_t)h) << 16);
}
__device__ __forceinline__ float sigf(float x) {
  return 1.0f / (1.0f + expf(-x));
}
__device__ __forceinline__ f32x4 mfma16(bf16x8 a, bf16x8 b, f32x4 c) {
  return __builtin_amdgcn_mfma_f32_16x16x32_bf16(a, b, c, 0, 0, 0);
}

// ---------------- threefry2x32 (JAX-exact, 20 rounds) ----------------
__device__ __forceinline__ uint32_t rotl32(uint32_t v, int r) {
  return (v << r) | (v >> (32 - r));
}
__device__ __forceinline__ void threefry2x32(uint32_t k0, uint32_t k1,
                                             uint32_t x0, uint32_t x1,
                                             uint32_t& o0, uint32_t& o1) {
  uint32_t k2 = k0 ^ k1 ^ 0x1BD11BDAu;
  x0 += k0; x1 += k1;
  x0 += x1; x1 = rotl32(x1, 13); x1 ^= x0;
  x0 += x1; x1 = rotl32(x1, 15); x1 ^= x0;
  x0 += x1; x1 = rotl32(x1, 26); x1 ^= x0;
  x0 += x1; x1 = rotl32(x1, 6);  x1 ^= x0;
  x0 += k1; x1 += k2 + 1u;
  x0 += x1; x1 = rotl32(x1, 17); x1 ^= x0;
  x0 += x1; x1 = rotl32(x1, 29); x1 ^= x0;
  x0 += x1; x1 = rotl32(x1, 16); x1 ^= x0;
  x0 += x1; x1 = rotl32(x1, 24); x1 ^= x0;
  x0 += k2; x1 += k0 + 2u;
  x0 += x1; x1 = rotl32(x1, 13); x1 ^= x0;
  x0 += x1; x1 = rotl32(x1, 15); x1 ^= x0;
  x0 += x1; x1 = rotl32(x1, 26); x1 ^= x0;
  x0 += x1; x1 = rotl32(x1, 6);  x1 ^= x0;
  x0 += k0; x1 += k1 + 3u;
  x0 += x1; x1 = rotl32(x1, 17); x1 ^= x0;
  x0 += x1; x1 = rotl32(x1, 29); x1 ^= x0;
  x0 += x1; x1 = rotl32(x1, 16); x1 ^= x0;
  x0 += x1; x1 = rotl32(x1, 24); x1 ^= x0;
  x0 += k1; x1 += k2 + 4u;
  x0 += x1; x1 = rotl32(x1, 13); x1 ^= x0;
  x0 += x1; x1 = rotl32(x1, 15); x1 ^= x0;
  x0 += x1; x1 = rotl32(x1, 26); x1 ^= x0;
  x0 += x1; x1 = rotl32(x1, 6);  x1 ^= x0;
  x0 += k2; x1 += k0 + 5u;
  o0 = x0; o1 = x1;
}

__device__ __forceinline__ float gumbel_from_bits(uint32_t bits) {
  float u = __uint_as_float((bits >> 9) | 0x3f800000u) - 1.0f;
  if (u == 0.0f) u = 1.17549435e-38f;
  return -logf(-logf(u));
}

// ---------------- prelude kernels ----------------
__global__ __launch_bounds__(256) void init_state_kernel() {
  int i = blockIdx.x * 256 + threadIdx.x;  // 1024 blocks -> 262144 threads
  if (i < BB * HH) { g_h0f[i] = 0.0f; g_h1f[i] = 0.0f; }
  if (i < 262144) {  // both parities+planes: 524288 shorts = 262144 u32
    ((uint32_t*)g_h0p)[i] = 0u;
    ((uint32_t*)g_h1p)[i] = 0u;
  }
  if (i < 2 * BB * 16) ((unsigned*)g_avail)[i] = 0xFFFFFFFFu;
  if (i < NN * 16) ((int*)g_done)[i] = 0;
  if (i < BB) { g_lp[i] = 0.0f; g_idx[i] = 0; }
}

__global__ __launch_bounds__(256) void ones_row_kernel(
    const float* __restrict__ W_ih0, const float* __restrict__ b_ih0) {
  int j = blockIdx.x * 256 + threadIdx.x;
  if (j < G3) {
    const float* row = W_ih0 + (size_t)j * NN;
    float s = 0.0f;
    for (int k = 0; k < NN; ++k) s += row[k];
    g_ones[j] = s + b_ih0[j];
  }
}

__global__ __launch_bounds__(256) void transpose_kernel(
    const float* __restrict__ in) {
  __shared__ float tile[32][33];
  int bx = blockIdx.x;  // over NN, 16
  int by = blockIdx.y;  // over G3, 48
  int tx = threadIdx.x & 31;
  int ty = threadIdx.x >> 5;
  for (int i = 0; i < 32; i += 8)
    tile[ty + i][tx] = in[(size_t)(by * 32 + ty + i) * NN + bx * 32 + tx];
  __syncthreads();
  for (int i = 0; i < 32; i += 8)
    g_WihT[(size_t)(bx * 32 + ty + i) * G3 + by * 32 + tx] = tile[tx][ty + i];
}

__global__ __launch_bounds__(256) void split_kernel(
    const float* __restrict__ W, short* __restrict__ dst, int rows,
    int plane) {
  int i = blockIdx.x * 256 + threadIdx.x;  // rows*64 threads
  if (i >= rows * 64) return;
  int c = i >> 6;   // original W row
  int jb = i & 63;  // 8-elem k-chunk
  int ci = c & 15;
  int tile = (rows == G3) ? (((c & 511) >> 4) * 3 + (c >> 9)) : (c >> 4);
  int S = jb >> 2, qu = jb & 3;
  int off = (tile * 16 + S) * 512 + qu * 128 + ci * 8;
  const float* src = W + (size_t)c * 512 + jb * 8;
  float v[8];
  *(float4*)v = *(const float4*)src;
  *(float4*)(v + 4) = *(const float4*)(src + 4);
  short hb[8], lb[8];
#pragma unroll
  for (int e = 0; e < 8; ++e) {
    unsigned short h = bf16_rne(v[e]);
    hb[e] = (short)h;
    lb[e] = (short)bf16_rne(v[e] - bf16_to_f(h));
  }
  *(bf16x8*)(dst + off) = *(const bf16x8*)hb;
  *(bf16x8*)(dst + plane + off) = *(const bf16x8*)lb;
}

// ---------------- K0: tail-only sampler replay (t == NN) --------------------
// grid 16 blocks (one per mt), 256 threads: 16 rows x 16 lanes (32 cols each).
__global__ __launch_bounds__(256) void k0_sample(
    int t, const float* __restrict__ b_out, float* __restrict__ out_perm,
    float* __restrict__ out_lp) {
  const int mt = blockIdx.x;
  const int tid = threadIdx.x;
  if (t == 0) return;
  const int tp = t - 1;
  const int rr = tid >> 4, l16 = tid & 15;
  const int b = mt * 16 + rr;
  const float* lrow = g_logits[tp & 1] + b * NN;
  const float* grow = g_gum[tp & 1] + b * NN;
  unsigned aw = g_avail[tp & 1][b * 16 + l16];

  float best = -1.0f / 0.0f;
  int bi = 0;
  float sum = 0.0f;
  for (int k = 0; k < 32; ++k) {
    int c = l16 * 32 + k;
    float l = lrow[c] + b_out[c];
    bool av = (aw >> k) & 1u;
    float ml = av ? l : -1.0e9f;
    float v = grow[c] + ml;
    if (v > best || (v == best && c < bi)) { best = v; bi = c; }
    sum += av ? expf(l) : 0.0f;  // == sum exp(masked) since exp(-1e9)=0
  }
  __shared__ float sv[256];
  __shared__ int si[256];
  __shared__ float ss[256];
  sv[tid] = best; si[tid] = bi; ss[tid] = sum;
  __syncthreads();
  for (int s = 8; s > 0; s >>= 1) {
    if (l16 < s) {
      float v2 = sv[tid + s]; int i2 = si[tid + s];
      if (v2 > sv[tid] || (v2 == sv[tid] && i2 < si[tid])) {
        sv[tid] = v2; si[tid] = i2;
      }
      ss[tid] += ss[tid + s];
    }
    __syncthreads();
  }
  const int sel = si[rr * 16];
  const float ssum = ss[rr * 16];
  unsigned nw = aw;
  if ((sel >> 5) == l16) nw &= ~(1u << (sel & 31));
  g_avail[t & 1][b * 16 + l16] = nw;
  if (l16 == 0) {
    float lsel = lrow[sel] + b_out[sel];
    float p = expf(lsel) / ssum;
    float lpn = g_lp[b] + logf(p + 1e-9f);
    g_lp[b] = lpn;
    out_lp[b] = lpn;
    g_idx[b] = sel;
    out_perm[(size_t)b * NN * NN + (size_t)tp * NN + sel] = 1.0f;
  }
}

// ---------------- merged per-step kernel ------------------------------------
// grid 256 = 16 mt x 16 nb, 256 threads (1 block/CU -> all co-resident).
// Phase A (all blocks) == R6 k1: zero logits slice; nb<8 replicate sampler
// (nb==0 does side-effect writes) then cell0 -> h0'; nb>=8 compute gh1;
// nb>=8 && mt<8 also generate gumbel(t) (verified in R7).
// Fence: each block signals g_done[t][mt] after __syncthreads+threadfence.
// Phase B (bid<128) == R6 k2: wait for its mt2's 16 producers, then
// cell1 -> h1' + atomic logits into g_logits[t&1].
__global__ __launch_bounds__(256) void step_kernel(
    int t, const float* __restrict__ b_ih0, const float* __restrict__ b_hh0,
    const float* __restrict__ b_hh1, const float* __restrict__ b_ih1,
    const float* __restrict__ b_out, float* __restrict__ out_perm,
    float* __restrict__ out_lp) {
  const int bid = blockIdx.x;
  const int mt = bid >> 4, nb = bid & 15;
  const int tid = threadIdx.x;

  __shared__ float sv[256];
  __shared__ int si[256];
  __shared__ float ss[256];
  __shared__ int sel16[16];
  __shared__ short Lh[1024], Ll[1024];

  // ---- phase A ----
  {  // zero this block's (mt,nb) slice of logits[t&1]: 16 rows x 32 cols
    float* lz = g_logits[t & 1];
    const int e0 = tid, e1 = tid + 256;
    lz[(mt * 16 + (e0 >> 5)) * NN + nb * 32 + (e0 & 31)] = 0.0f;
    lz[(mt * 16 + (e1 >> 5)) * NN + nb * 32 + (e1 & 31)] = 0.0f;
  }

  if (t > 0 && nb < 8) {  // replicated sampler (block-uniform branch)
    const int tp = t - 1;
    const int rr = tid >> 4, l16 = tid & 15;
    const int b = mt * 16 + rr;
    const float* lrow = g_logits[tp & 1] + b * NN;
    const float* grow = g_gum[tp & 1] + b * NN;
    unsigned aw = g_avail[tp & 1][b * 16 + l16];

    float best = -1.0f / 0.0f;
    int bi = 0;
    float sum = 0.0f;
    for (int k = 0; k < 32; ++k) {
      int c = l16 * 32 + k;
      float l = lrow[c] + b_out[c];
      bool av = (aw >> k) & 1u;
      float ml = av ? l : -1.0e9f;
      float v = grow[c] + ml;
      if (v > best || (v == best && c < bi)) { best = v; bi = c; }
      sum += av ? expf(l) : 0.0f;
    }
    sv[tid] = best; si[tid] = bi; ss[tid] = sum;
    __syncthreads();
    for (int s = 8; s > 0; s >>= 1) {
      if (l16 < s) {
        float v2 = sv[tid + s]; int i2 = si[tid + s];
        if (v2 > sv[tid] || (v2 == sv[tid] && i2 < si[tid])) {
          sv[tid] = v2; si[tid] = i2;
        }
        ss[tid] += ss[tid + s];
      }
      __syncthreads();
    }
    const int sel = si[rr * 16];
    if (l16 == 0) sel16[rr] = sel;
    if (nb == 0) {  // side-effect writes (round-0 k0's exact write set)
      unsigned nw = aw;
      if ((sel >> 5) == l16) nw &= ~(1u << (sel & 31));
      g_avail[t & 1][b * 16 + l16] = nw;
      if (l16 == 0) {
        const float ssum = ss[rr * 16];
        float lsel = lrow[sel] + b_out[sel];
        float p = expf(lsel) / ssum;
        float lpn = g_lp[b] + logf(p + 1e-9f);
        g_lp[b] = lpn;
        out_lp[b] = lpn;
        out_perm[(size_t)b * NN * NN + (size_t)tp * NN + sel] = 1.0f;
      }
    }
    __syncthreads();  // sel16 visible to all roles
  }

  {
    const int w = tid >> 6, ln = tid & 63;
    const int ci = ln & 15, qu = ln >> 4;
    const int lnoff = ln * 8;
    const int rb = t & 1, wb = rb ^ 1;

    f32x4 z = (f32x4){0.f, 0.f, 0.f, 0.f};
    f32x4 acc[3] = {z, z, z};

    const int u = (nb & 7) * 4 + w;
    const short* Ap = (nb < 8) ? g_h0p[rb] : g_h1p[rb];
    const short* Wp = (nb < 8) ? g_Whh0 : g_Whh1;

#pragma unroll
    for (int S = 0; S < 16; ++S) {
      const int aoff = mt * 8192 + S * 512 + lnoff;
      bf16x8 ah = *(const bf16x8*)(Ap + aoff);
      bf16x8 al = *(const bf16x8*)(Ap + 131072 + aoff);
#pragma unroll
      for (int g = 0; g < 3; ++g) {
        const short* wp = Wp + ((u * 3 + g) * 16 + S) * 512 + lnoff;
        bf16x8 bh = *(const bf16x8*)wp;
        bf16x8 bl = *(const bf16x8*)(wp + 786432);
        acc[g] = mfma16(ah, bh, acc[g]);
        acc[g] = mfma16(ah, bl, acc[g]);
        acc[g] = mfma16(al, bh, acc[g]);
      }
    }

    const int h = u * 16 + ci;
    if (nb < 8) {
      const float br = b_hh0[h], bz = b_hh0[HH + h], bn = b_hh0[2 * HH + h];
      const float bi0 = b_ih0[h], bi1 = b_ih0[HH + h], bi2 = b_ih0[2 * HH + h];
#pragma unroll
      for (int r = 0; r < 4; ++r) {
        const int b = mt * 16 + qu * 4 + r;
        float ir, iz, in_;
        if (t == 0) {
          ir = g_ones[h]; iz = g_ones[HH + h]; in_ = g_ones[2 * HH + h];
        } else {
          const float* wr_ = g_WihT + (size_t)sel16[qu * 4 + r] * G3;
          ir = wr_[h] + bi0;
          iz = wr_[HH + h] + bi1;
          in_ = wr_[2 * HH + h] + bi2;
        }
        float rr_ = sigf(ir + acc[0][r] + br);
        float zz = sigf(iz + acc[1][r] + bz);
        float ng = tanhf(in_ + rr_ * (acc[2][r] + bn));
        const int o = b * HH + h;
        float hn = (1.f - zz) * ng + zz * g_h0f[o];
        g_h0f[o] = hn;
        const int off = (b >> 4) * 8192 + (h >> 5) * 512 + ((h >> 3) & 3) * 128 +
                        (b & 15) * 8 + (h & 7);
        unsigned short hi = bf16_rne(hn);
        g_h0p[wb][off] = (short)hi;
        g_h0p[wb][131072 + off] = (short)bf16_rne(hn - bf16_to_f(hi));
      }
    } else {
      const float c0 = b_hh1[h], c1 = b_hh1[HH + h], c2 = b_hh1[2 * HH + h];
#pragma unroll
      for (int r = 0; r < 4; ++r) {
        const int b = mt * 16 + qu * 4 + r;
        float* base = g_gh1 + (size_t)b * G3;
        base[h] = acc[0][r] + c0;
        base[512 + h] = acc[1][r] + c1;
        base[1024 + h] = acc[2][r] + c2;
      }
    }

    // gumbel(t): nb>=8 && mt<8 blocks (verified placement, R7)
    if (nb >= 8 && mt < 8) {
      const int nb2 = nb & 7;
      uint32_t tp_ = (uint32_t)(t & 255);
      uint32_t a0, a1, c0, c1;
      threefry2x32(0u, 42u, 2u * tp_, 2u * tp_ + 512u, a0, a1);
      threefry2x32(0u, 42u, 2u * tp_ + 1u, 2u * tp_ + 1u + 512u, c0, c1);
      uint32_t sk0 = (t < 256) ? a0 : a1;
      uint32_t sk1 = (t < 256) ? c0 : c1;
      float* G = g_gum[t & 1];
      for (int e = tid; e < 1024; e += 256) {
        const int r16 = e >> 6;
        const int c = nb2 * 64 + (e & 63);
        const int b = mt * 16 + r16;  // < 128
        uint32_t cnt = (uint32_t)b * 512u + (uint32_t)c;
        uint32_t r0, r1;
        threefry2x32(sk0, sk1, cnt, cnt + 65536u, r0, r1);
        G[b * NN + c] = gumbel_from_bits(r0);
        G[(b + 128) * NN + c] = gumbel_from_bits(r1);
      }
    }
  }

  // ---- fence: signal phase-A completion for this mt ----
  __syncthreads();  // drain all of this block's phase-A stores (vmcnt)
  if (tid == 0) {
    __threadfence();  // agent-scope writeback so other XCDs see our stores
    __hip_atomic_fetch_add(&g_done[t][mt], 1, __ATOMIC_RELEASE,
                           __HIP_MEMORY_SCOPE_AGENT);
  }

  if (bid >= 128) return;

  // ---- phase B (R6 k2 verbatim; mt2 = bid>>3, nbk = bid&7) ----
  const int mt2 = bid >> 3, nbk = bid & 7;
  if (tid == 0) {
    while (__hip_atomic_load(&g_done[t][mt2], __ATOMIC_ACQUIRE,
                             __HIP_MEMORY_SCOPE_AGENT) < 16) {
      __builtin_amdgcn_s_sleep(8);
    }
  }
  __syncthreads();

  {
    const int w = tid >> 6, ln = tid & 63;
    const int ci = ln & 15, qu = ln >> 4;
    const int lnoff = ln * 8;
    const int wb = (t & 1) ^ 1;

    f32x4 z = (f32x4){0.f, 0.f, 0.f, 0.f};
    f32x4 acc[3] = {z, z, z};
    const int u = nbk * 4 + w;

#pragma unroll
    for (int S = 0; S < 16; ++S) {
      const int aoff = mt2 * 8192 + S * 512 + lnoff;
      bf16x8 ah = *(const bf16x8*)(g_h0p[wb] + aoff);
      bf16x8 al = *(const bf16x8*)(g_h0p[wb] + 131072 + aoff);
#pragma unroll
      for (int g = 0; g < 3; ++g) {
        const short* wp = g_Wih1 + ((u * 3 + g) * 16 + S) * 512 + lnoff;
        bf16x8 bh = *(const bf16x8*)wp;
        bf16x8 bl = *(const bf16x8*)(wp + 786432);
        acc[g] = mfma16(ah, bh, acc[g]);
        acc[g] = mfma16(ah, bl, acc[g]);
        acc[g] = mfma16(al, bh, acc[g]);
      }
    }

    const int h = u * 16 + ci;
    const float bi0 = b_ih1[h], bi1 = b_ih1[HH + h], bi2 = b_ih1[2 * HH + h];
    float hn[4];
#pragma unroll
    for (int r = 0; r < 4; ++r) {
      const int b = mt2 * 16 + qu * 4 + r;
      const float* base = g_gh1 + (size_t)b * G3;
      float rr_ = sigf(acc[0][r] + bi0 + base[h]);
      float zz = sigf(acc[1][r] + bi1 + base[512 + h]);
      float ng = tanhf(acc[2][r] + bi2 + rr_ * base[1024 + h]);
      const int o = b * HH + h;
      float v = (1.f - zz) * ng + zz * g_h1f[o];
      g_h1f[o] = v;
      hn[r] = v;
      const int off = (b >> 4) * 8192 + (h >> 5) * 512 + ((h >> 3) & 3) * 128 +
                      (b & 15) * 8 + (h & 7);
      unsigned short hi = bf16_rne(v);
      g_h1p[wb][off] = (short)hi;
      g_h1p[wb][131072 + off] = (short)bf16_rne(v - bf16_to_f(hi));
    }

    // transpose h1' (C-layout) -> A-fragment LDS for the partial-logits MFMA
    const int kk = w * 16 + ci;  // block-local k (h col) 0..63
#pragma unroll
    for (int r = 0; r < 4; ++r) {
      const int m = qu * 4 + r;
      const int off = (kk >> 5) * 512 + ((kk >> 3) & 3) * 128 + m * 8 + (kk & 7);
      unsigned short hi = bf16_rne(hn[r]);
      Lh[off] = (short)hi;
      Ll[off] = (short)bf16_rne(hn[r] - bf16_to_f(hi));
    }
    __syncthreads();

    f32x4 acc2[8] = {z, z, z, z, z, z, z, z};
#pragma unroll
    for (int S2 = 0; S2 < 2; ++S2) {
      bf16x8 ah = *(const bf16x8*)&Lh[S2 * 512 + lnoff];
      bf16x8 al = *(const bf16x8*)&Ll[S2 * 512 + lnoff];
#pragma unroll
      for (int j = 0; j < 8; ++j) {
        const int nt = w * 8 + j;
        const short* wp = g_Wout + (nt * 16 + nbk * 2 + S2) * 512 + lnoff;
        bf16x8 bh = *(const bf16x8*)wp;
        bf16x8 bl = *(const bf16x8*)(wp + 262144);
        acc2[j] = mfma16(ah, bh, acc2[j]);
        acc2[j] = mfma16(ah, bl, acc2[j]);
        acc2[j] = mfma16(al, bh, acc2[j]);
      }
    }
    float* Ldst = g_logits[t & 1];
#pragma unroll
    for (int j = 0; j < 8; ++j) {
      const int n = (w * 8 + j) * 16 + ci;
#pragma unroll
      for (int r = 0; r < 4; ++r) {
        const int b = mt2 * 16 + qu * 4 + r;
        atomicAdd(&Ldst[b * NN + n], acc2[j][r]);
      }
    }
  }
}

// ---------------- host ----------------
extern "C" void kernel_launch(void* const* d_in, const int* in_sizes, int n_in,
                              void* d_out, int out_size, void* d_ws,
                              size_t ws_size, hipStream_t stream) {
  (void)in_sizes; (void)n_in; (void)d_ws; (void)ws_size;
  const float* W_ih0 = (const float*)d_in[1];
  const float* W_hh0 = (const float*)d_in[2];
  const float* b_ih0 = (const float*)d_in[3];
  const float* b_hh0 = (const float*)d_in[4];
  const float* W_ih1 = (const float*)d_in[5];
  const float* W_hh1 = (const float*)d_in[6];
  const float* b_ih1 = (const float*)d_in[7];
  const float* b_hh1 = (const float*)d_in[8];
  const float* W_out = (const float*)d_in[9];
  const float* b_out = (const float*)d_in[10];

  float* out = (float*)d_out;
  float* out_lp = out + (size_t)BB * NN * NN;

  hipMemsetAsync(d_out, 0, (size_t)out_size * sizeof(float), stream);
  init_state_kernel<<<1024, 256, 0, stream>>>();
  ones_row_kernel<<<6, 256, 0, stream>>>(W_ih0, b_ih0);
  transpose_kernel<<<dim3(16, 48), 256, 0, stream>>>(W_ih0);

  short* whh0; hipGetSymbolAddress((void**)&whh0, HIP_SYMBOL(g_Whh0));
  short* whh1; hipGetSymbolAddress((void**)&whh1, HIP_SYMBOL(g_Whh1));
  short* wih1; hipGetSymbolAddress((void**)&wih1, HIP_SYMBOL(g_Wih1));
  short* wout; hipGetSymbolAddress((void**)&wout, HIP_SYMBOL(g_Wout));
  split_kernel<<<384, 256, 0, stream>>>(W_hh0, whh0, G3, 786432);
  split_kernel<<<384, 256, 0, stream>>>(W_hh1, whh1, G3, 786432);
  split_kernel<<<384, 256, 0, stream>>>(W_ih1, wih1, G3, 786432);
  split_kernel<<<128, 256, 0, stream>>>(W_out, wout, NN, 262144);

  for (int t = 0; t < NN; ++t) {
    step_kernel<<<256, 256, 0, stream>>>(t, b_ih0, b_hh0, b_hh1, b_ih1,
                                         b_out, out, out_lp);
  }
  // tail: replay and finalize step 511
  k0_sample<<<16, 256, 0, stream>>>(NN, b_out, out, out_lp);
}

// Round 9
// 26879.260 us; speedup vs baseline: 1.5182x; 1.5182x over previous
//
#include <hip/hip_runtime.h>
#include <cstdint>
#include <cstddef>

// B=256 batch, n=512 classes/steps, H=512 hidden, 3H=1536.
#define BB 256
#define NN 512
#define HH 512
#define G3 1536

typedef short bf16x8 __attribute__((ext_vector_type(8)));
typedef float f32x4 __attribute__((ext_vector_type(4)));

// ---------------- static device state ----------------
// Weight planes (hi then lo), MFMA fragment order. 1536-row weights use
// GATE-INTERLEAVED tiles: tile(c) = ((c&511)>>4)*3 + (c>>9)  (c = W row):
// tile u*3+g holds rows {g*512 + u*16 + i}. W_out: tile = c>>4.
// Fragment offset: (tile*16 + S)*512 + qu*128 + ci*8 + j   (S=k>>5 etc).
__device__ __align__(16) short g_Whh0[2 * 786432];
__device__ __align__(16) short g_Whh1[2 * 786432];
__device__ __align__(16) short g_Wih1[2 * 786432];
__device__ __align__(16) short g_Wout[2 * 262144];
// h-state bf16 hi/lo planes, double buffered by parity; A-fragment order:
// off(b,h) = (b>>4)*8192 + (h>>5)*512 + ((h>>3)&3)*128 + (b&15)*8 + (h&7)
__device__ __align__(16) short g_h0p[2][2 * 131072];
__device__ __align__(16) short g_h1p[2][2 * 131072];
__device__ __align__(16) float g_h0f[BB * HH];   // exact fp32 hold terms
__device__ __align__(16) float g_h1f[BB * HH];   // (same-thread-role RMW)
__device__ __align__(16) float g_gh1[BB * G3];   // [b][g*512+h], incl b_hh1
__device__ __align__(16) float g_logits[2][BB * NN];  // atomic partial sums
__device__ __align__(16) float g_gum[2][BB * NN];     // per-step gumbels
__device__ __align__(16) float g_WihT[NN * G3];  // W_ih0^T rows for gather
__device__ __align__(16) float g_ones[G3];       // gi0 at t=0 (incl b_ih0)
__device__ float g_lp[BB];
__device__ unsigned g_avail[2][BB * 16];
__device__ int g_idx[BB];

// ---------------- bf16 hi/lo helpers ----------------
__device__ __forceinline__ unsigned short bf16_rne(float f) {
  uint32_t u = __float_as_uint(f);
  uint32_t r = u + 0x7FFFu + ((u >> 16) & 1u);
  return (unsigned short)(r >> 16);
}
__device__ __forceinline__ float bf16_to_f(unsigned short h) {
  return __uint_as_float(((uint32_t)h) << 16);
}
__device__ __forceinline__ float sigf(float x) {
  return 1.0f / (1.0f + expf(-x));
}
__device__ __forceinline__ f32x4 mfma16(bf16x8 a, bf16x8 b, f32x4 c) {
  return __builtin_amdgcn_mfma_f32_16x16x32_bf16(a, b, c, 0, 0, 0);
}

// ---------------- threefry2x32 (JAX-exact, 20 rounds) ----------------
__device__ __forceinline__ uint32_t rotl32(uint32_t v, int r) {
  return (v << r) | (v >> (32 - r));
}
__device__ __forceinline__ void threefry2x32(uint32_t k0, uint32_t k1,
                                             uint32_t x0, uint32_t x1,
                                             uint32_t& o0, uint32_t& o1) {
  uint32_t k2 = k0 ^ k1 ^ 0x1BD11BDAu;
  x0 += k0; x1 += k1;
  x0 += x1; x1 = rotl32(x1, 13); x1 ^= x0;
  x0 += x1; x1 = rotl32(x1, 15); x1 ^= x0;
  x0 += x1; x1 = rotl32(x1, 26); x1 ^= x0;
  x0 += x1; x1 = rotl32(x1, 6);  x1 ^= x0;
  x0 += k1; x1 += k2 + 1u;
  x0 += x1; x1 = rotl32(x1, 17); x1 ^= x0;
  x0 += x1; x1 = rotl32(x1, 29); x1 ^= x0;
  x0 += x1; x1 = rotl32(x1, 16); x1 ^= x0;
  x0 += x1; x1 = rotl32(x1, 24); x1 ^= x0;
  x0 += k2; x1 += k0 + 2u;
  x0 += x1; x1 = rotl32(x1, 13); x1 ^= x0;
  x0 += x1; x1 = rotl32(x1, 15); x1 ^= x0;
  x0 += x1; x1 = rotl32(x1, 26); x1 ^= x0;
  x0 += x1; x1 = rotl32(x1, 6);  x1 ^= x0;
  x0 += k0; x1 += k1 + 3u;
  x0 += x1; x1 = rotl32(x1, 17); x1 ^= x0;
  x0 += x1; x1 = rotl32(x1, 29); x1 ^= x0;
  x0 += x1; x1 = rotl32(x1, 16); x1 ^= x0;
  x0 += x1; x1 = rotl32(x1, 24); x1 ^= x0;
  x0 += k1; x1 += k2 + 4u;
  x0 += x1; x1 = rotl32(x1, 13); x1 ^= x0;
  x0 += x1; x1 = rotl32(x1, 15); x1 ^= x0;
  x0 += x1; x1 = rotl32(x1, 26); x1 ^= x0;
  x0 += x1; x1 = rotl32(x1, 6);  x1 ^= x0;
  x0 += k2; x1 += k0 + 5u;
  o0 = x0; o1 = x1;
}

__device__ __forceinline__ float gumbel_from_bits(uint32_t bits) {
  float u = __uint_as_float((bits >> 9) | 0x3f800000u) - 1.0f;
  if (u == 0.0f) u = 1.17549435e-38f;
  return -logf(-logf(u));
}

// ---------------- prelude kernels ----------------
__global__ __launch_bounds__(256) void init_state_kernel() {
  int i = blockIdx.x * 256 + threadIdx.x;  // 1024 blocks -> 262144 threads
  if (i < BB * HH) { g_h0f[i] = 0.0f; g_h1f[i] = 0.0f; }
  if (i < 262144) {  // both parities+planes: 524288 shorts = 262144 u32
    ((uint32_t*)g_h0p)[i] = 0u;
    ((uint32_t*)g_h1p)[i] = 0u;
  }
  if (i < 2 * BB * 16) ((unsigned*)g_avail)[i] = 0xFFFFFFFFu;
  if (i < BB) { g_lp[i] = 0.0f; g_idx[i] = 0; }
}

__global__ __launch_bounds__(256) void ones_row_kernel(
    const float* __restrict__ W_ih0, const float* __restrict__ b_ih0) {
  int j = blockIdx.x * 256 + threadIdx.x;
  if (j < G3) {
    const float* row = W_ih0 + (size_t)j * NN;
    float s = 0.0f;
    for (int k = 0; k < NN; ++k) s += row[k];
    g_ones[j] = s + b_ih0[j];
  }
}

__global__ __launch_bounds__(256) void transpose_kernel(
    const float* __restrict__ in) {
  __shared__ float tile[32][33];
  int bx = blockIdx.x;  // over NN, 16
  int by = blockIdx.y;  // over G3, 48
  int tx = threadIdx.x & 31;
  int ty = threadIdx.x >> 5;
  for (int i = 0; i < 32; i += 8)
    tile[ty + i][tx] = in[(size_t)(by * 32 + ty + i) * NN + bx * 32 + tx];
  __syncthreads();
  for (int i = 0; i < 32; i += 8)
    g_WihT[(size_t)(bx * 32 + ty + i) * G3 + by * 32 + tx] = tile[tx][ty + i];
}

__global__ __launch_bounds__(256) void split_kernel(
    const float* __restrict__ W, short* __restrict__ dst, int rows,
    int plane) {
  int i = blockIdx.x * 256 + threadIdx.x;  // rows*64 threads
  if (i >= rows * 64) return;
  int c = i >> 6;   // original W row
  int jb = i & 63;  // 8-elem k-chunk
  int ci = c & 15;
  int tile = (rows == G3) ? (((c & 511) >> 4) * 3 + (c >> 9)) : (c >> 4);
  int S = jb >> 2, qu = jb & 3;
  int off = (tile * 16 + S) * 512 + qu * 128 + ci * 8;
  const float* src = W + (size_t)c * 512 + jb * 8;
  float v[8];
  *(float4*)v = *(const float4*)src;
  *(float4*)(v + 4) = *(const float4*)(src + 4);
  short hb[8], lb[8];
#pragma unroll
  for (int e = 0; e < 8; ++e) {
    unsigned short h = bf16_rne(v[e]);
    hb[e] = (short)h;
    lb[e] = (short)bf16_rne(v[e] - bf16_to_f(h));
  }
  *(bf16x8*)(dst + off) = *(const bf16x8*)hb;
  *(bf16x8*)(dst + plane + off) = *(const bf16x8*)lb;
}

// ---------------- K0: tail-only sampler replay (t == NN, R6 verbatim) ------
__global__ __launch_bounds__(256) void k0_sample(
    int t, const float* __restrict__ b_out, float* __restrict__ out_perm,
    float* __restrict__ out_lp) {
  const int mt = blockIdx.x;
  const int tid = threadIdx.x;
  if (t < NN) {
    float* lz = g_logits[t & 1] + mt * 16 * NN;
    for (int i = tid; i < 16 * NN; i += 256) lz[i] = 0.0f;
  }
  if (t == 0) return;
  const int tp = t - 1;
  const int rr = tid >> 4, l16 = tid & 15;
  const int b = mt * 16 + rr;
  const float* lrow = g_logits[tp & 1] + b * NN;
  const float* grow = g_gum[tp & 1] + b * NN;
  unsigned aw = g_avail[tp & 1][b * 16 + l16];

  float best = -1.0f / 0.0f;
  int bi = 0;
  float sum = 0.0f;
  for (int k = 0; k < 32; ++k) {
    int c = l16 * 32 + k;
    float l = lrow[c] + b_out[c];
    bool av = (aw >> k) & 1u;
    float ml = av ? l : -1.0e9f;
    float v = grow[c] + ml;
    if (v > best || (v == best && c < bi)) { best = v; bi = c; }
    sum += av ? expf(l) : 0.0f;  // == sum exp(masked) since exp(-1e9)=0
  }
  __shared__ float sv[256];
  __shared__ int si[256];
  __shared__ float ss[256];
  sv[tid] = best; si[tid] = bi; ss[tid] = sum;
  __syncthreads();
  for (int s = 8; s > 0; s >>= 1) {
    if (l16 < s) {
      float v2 = sv[tid + s]; int i2 = si[tid + s];
      if (v2 > sv[tid] || (v2 == sv[tid] && i2 < si[tid])) {
        sv[tid] = v2; si[tid] = i2;
      }
      ss[tid] += ss[tid + s];
    }
    __syncthreads();
  }
  const int sel = si[rr * 16];
  const float ssum = ss[rr * 16];
  unsigned nw = aw;
  if ((sel >> 5) == l16) nw &= ~(1u << (sel & 31));
  g_avail[t & 1][b * 16 + l16] = nw;
  if (l16 == 0) {
    float lsel = lrow[sel] + b_out[sel];
    float p = expf(lsel) / ssum;
    float lpn = g_lp[b] + logf(p + 1e-9f);
    g_lp[b] = lpn;
    out_lp[b] = lpn;
    g_idx[b] = sel;
    out_perm[(size_t)b * NN * NN + (size_t)tp * NN + sel] = 1.0f;
  }
}

// ---------------- K1: sampler prologue + cell0 (nb<8) || gh1 (nb>=8) -------
// grid 256 = 16 mt x 16 nb, 512 threads (8 waves: 2 waves/SIMD).
// Wave-halves split the K dim (S=0..7 vs 8..15); 12KB LDS combine, 1 barrier.
// Sampler: waves 0-3 only, barrier-free 16-lane shfl_xor butterfly
// (bit-identical association to the R6 shared tree). Waves 4-7 start the
// weight-streaming MFMA loop immediately.
__global__ __launch_bounds__(512) void k1_layer0(
    int t, const float* __restrict__ b_ih0, const float* __restrict__ b_hh0,
    const float* __restrict__ b_hh1, const float* __restrict__ b_out,
    float* __restrict__ out_perm, float* __restrict__ out_lp) {
  const int bid = blockIdx.x;
  const int mt = bid >> 4, nb = bid & 15;
  const int tid = threadIdx.x;
  const int half = tid >> 8;      // K-split half
  const int t8 = tid & 255;

  __shared__ int sel16[16];
  __shared__ float accsh[3][4][256];

  // zero this block's (mt,nb) slice of logits[t&1]: 16 rows x 32 cols
  {
    float* lz = g_logits[t & 1];
    lz[(mt * 16 + (tid >> 5)) * NN + nb * 32 + (tid & 31)] = 0.0f;
  }

  if (t > 0 && nb < 8 && tid < 256) {  // replicated sampler, barrier-free
    const int tp = t - 1;
    const int rr = tid >> 4, l16 = tid & 15;
    const int b = mt * 16 + rr;
    const float* lrow = g_logits[tp & 1] + b * NN;
    const float* grow = g_gum[tp & 1] + b * NN;
    unsigned aw = g_avail[tp & 1][b * 16 + l16];

    float best = -1.0f / 0.0f;
    int bi = 0;
    float sum = 0.0f;
    for (int k = 0; k < 32; ++k) {
      int c = l16 * 32 + k;
      float l = lrow[c] + b_out[c];
      bool av = (aw >> k) & 1u;
      float ml = av ? l : -1.0e9f;
      float v = grow[c] + ml;
      if (v > best || (v == best && c < bi)) { best = v; bi = c; }
      sum += av ? expf(l) : 0.0f;
    }
    // 16-lane butterfly: same pairing/association as the shared tree
#pragma unroll
    for (int s = 8; s > 0; s >>= 1) {
      float ov = __shfl_xor(best, s, 16);
      int oi = __shfl_xor(bi, s, 16);
      float os = __shfl_xor(sum, s, 16);
      if (ov > best || (ov == best && oi < bi)) { best = ov; bi = oi; }
      sum += os;
    }
    if (l16 == 0) sel16[rr] = bi;  // visible after the combine barrier
    if (nb == 0) {  // side-effect writes (round-0 k0's exact write set)
      unsigned nw = aw;
      if ((bi >> 5) == l16) nw &= ~(1u << (bi & 31));
      g_avail[t & 1][b * 16 + l16] = nw;
      if (l16 == 0) {
        float lsel = lrow[bi] + b_out[bi];
        float p = expf(lsel) / sum;
        float lpn = g_lp[b] + logf(p + 1e-9f);
        g_lp[b] = lpn;
        out_lp[b] = lpn;
        out_perm[(size_t)b * NN * NN + (size_t)tp * NN + bi] = 1.0f;
      }
    }
  }

  const int w = t8 >> 6, ln = t8 & 63;
  const int ci = ln & 15, qu = ln >> 4;
  const int lnoff = ln * 8;
  const int rb = t & 1, wb = rb ^ 1;

  f32x4 z = (f32x4){0.f, 0.f, 0.f, 0.f};
  f32x4 acc[3] = {z, z, z};

  const int u = (nb & 7) * 4 + w;
  const short* Ap = (nb < 8) ? g_h0p[rb] : g_h1p[rb];
  const short* Wp = (nb < 8) ? g_Whh0 : g_Whh1;
  const int Sbeg = half * 8;

#pragma unroll
  for (int So = 0; So < 8; ++So) {
    const int S = Sbeg + So;
    const int aoff = mt * 8192 + S * 512 + lnoff;
    bf16x8 ah = *(const bf16x8*)(Ap + aoff);
    bf16x8 al = *(const bf16x8*)(Ap + 131072 + aoff);
#pragma unroll
    for (int g = 0; g < 3; ++g) {
      const short* wp = Wp + ((u * 3 + g) * 16 + S) * 512 + lnoff;
      bf16x8 bh = *(const bf16x8*)wp;
      bf16x8 bl = *(const bf16x8*)(wp + 786432);
      acc[g] = mfma16(ah, bh, acc[g]);
      acc[g] = mfma16(ah, bl, acc[g]);
      acc[g] = mfma16(al, bh, acc[g]);
    }
  }

  // combine K-halves: half1 -> LDS, one barrier, half0 adds
  if (half == 1) {
#pragma unroll
    for (int g = 0; g < 3; ++g)
#pragma unroll
      for (int r = 0; r < 4; ++r) accsh[g][r][t8] = acc[g][r];
  }
  __syncthreads();

  if (tid < 256) {
#pragma unroll
    for (int g = 0; g < 3; ++g)
#pragma unroll
      for (int r = 0; r < 4; ++r) acc[g][r] += accsh[g][r][t8];

    const int h = u * 16 + ci;
    if (nb < 8) {
      const float br = b_hh0[h], bz = b_hh0[HH + h], bn = b_hh0[2 * HH + h];
      const float bi0 = b_ih0[h], bi1 = b_ih0[HH + h], bi2 = b_ih0[2 * HH + h];
#pragma unroll
      for (int r = 0; r < 4; ++r) {
        const int b = mt * 16 + qu * 4 + r;
        float ir, iz, in_;
        if (t == 0) {
          ir = g_ones[h]; iz = g_ones[HH + h]; in_ = g_ones[2 * HH + h];
        } else {
          const float* wr_ = g_WihT + (size_t)sel16[qu * 4 + r] * G3;
          ir = wr_[h] + bi0;
          iz = wr_[HH + h] + bi1;
          in_ = wr_[2 * HH + h] + bi2;
        }
        float rr_ = sigf(ir + acc[0][r] + br);
        float zz = sigf(iz + acc[1][r] + bz);
        float ng = tanhf(in_ + rr_ * (acc[2][r] + bn));
        const int o = b * HH + h;
        float hn = (1.f - zz) * ng + zz * g_h0f[o];
        g_h0f[o] = hn;
        const int off = (b >> 4) * 8192 + (h >> 5) * 512 +
                        ((h >> 3) & 3) * 128 + (b & 15) * 8 + (h & 7);
        unsigned short hi = bf16_rne(hn);
        g_h0p[wb][off] = (short)hi;
        g_h0p[wb][131072 + off] = (short)bf16_rne(hn - bf16_to_f(hi));
      }
    } else {
      const float c0 = b_hh1[h], c1 = b_hh1[HH + h], c2 = b_hh1[2 * HH + h];
#pragma unroll
      for (int r = 0; r < 4; ++r) {
        const int b = mt * 16 + qu * 4 + r;
        float* base = g_gh1 + (size_t)b * G3;
        base[h] = acc[0][r] + c0;
        base[512 + h] = acc[1][r] + c1;
        base[1024 + h] = acc[2][r] + c2;
      }
    }
  }

  // gumbel(t): nb>=8 && mt<8 blocks (R7-verified placement), all 512 threads
  if (nb >= 8 && mt < 8) {
    const int nb2 = nb & 7;
    uint32_t tp_ = (uint32_t)(t & 255);
    uint32_t a0, a1, c0, c1;
    threefry2x32(0u, 42u, 2u * tp_, 2u * tp_ + 512u, a0, a1);
    threefry2x32(0u, 42u, 2u * tp_ + 1u, 2u * tp_ + 1u + 512u, c0, c1);
    uint32_t sk0 = (t < 256) ? a0 : a1;
    uint32_t sk1 = (t < 256) ? c0 : c1;
    float* G = g_gum[t & 1];
    for (int e = tid; e < 1024; e += 512) {
      const int r16 = e >> 6;
      const int c = nb2 * 64 + (e & 63);
      const int b = mt * 16 + r16;  // < 128
      uint32_t cnt = (uint32_t)b * 512u + (uint32_t)c;
      uint32_t r0, r1;
      threefry2x32(sk0, sk1, cnt, cnt + 65536u, r0, r1);
      G[b * NN + c] = gumbel_from_bits(r0);
      G[(b + 128) * NN + c] = gumbel_from_bits(r1);
    }
  }
}

// ---------------- K2: gi1+cell1 -> h1' + partial logits ---------------------
// grid 128 = 16 mt x 8 nb, 512 threads. First GEMM K-split as in k1;
// second GEMM splits its 8 j-columns across wave-halves (atomics, no combine).
__global__ __launch_bounds__(512) void k2_layer1(
    int t, const float* __restrict__ b_ih1) {
  const int bid = blockIdx.x;
  const int mt = bid >> 3, nb = bid & 7;
  const int tid = threadIdx.x;
  const int half = tid >> 8;
  const int t8 = tid & 255;
  const int w = t8 >> 6, ln = t8 & 63;
  const int ci = ln & 15, qu = ln >> 4;
  const int lnoff = ln * 8;
  const int wb = (t & 1) ^ 1;

  __shared__ float accsh[3][4][256];
  __shared__ short Lh[1024], Ll[1024];

  f32x4 z = (f32x4){0.f, 0.f, 0.f, 0.f};
  f32x4 acc[3] = {z, z, z};
  const int u = nb * 4 + w;
  const int Sbeg = half * 8;

#pragma unroll
  for (int So = 0; So < 8; ++So) {
    const int S = Sbeg + So;
    const int aoff = mt * 8192 + S * 512 + lnoff;
    bf16x8 ah = *(const bf16x8*)(g_h0p[wb] + aoff);
    bf16x8 al = *(const bf16x8*)(g_h0p[wb] + 131072 + aoff);
#pragma unroll
    for (int g = 0; g < 3; ++g) {
      const short* wp = g_Wih1 + ((u * 3 + g) * 16 + S) * 512 + lnoff;
      bf16x8 bh = *(const bf16x8*)wp;
      bf16x8 bl = *(const bf16x8*)(wp + 786432);
      acc[g] = mfma16(ah, bh, acc[g]);
      acc[g] = mfma16(ah, bl, acc[g]);
      acc[g] = mfma16(al, bh, acc[g]);
    }
  }

  if (half == 1) {
#pragma unroll
    for (int g = 0; g < 3; ++g)
#pragma unroll
      for (int r = 0; r < 4; ++r) accsh[g][r][t8] = acc[g][r];
  }
  __syncthreads();

  if (tid < 256) {
#pragma unroll
    for (int g = 0; g < 3; ++g)
#pragma unroll
      for (int r = 0; r < 4; ++r) acc[g][r] += accsh[g][r][t8];

    const int h = u * 16 + ci;
    const float bi0 = b_ih1[h], bi1 = b_ih1[HH + h], bi2 = b_ih1[2 * HH + h];
    float hn[4];
#pragma unroll
    for (int r = 0; r < 4; ++r) {
      const int b = mt * 16 + qu * 4 + r;
      const float* base = g_gh1 + (size_t)b * G3;
      float rr_ = sigf(acc[0][r] + bi0 + base[h]);
      float zz = sigf(acc[1][r] + bi1 + base[512 + h]);
      float ng = tanhf(acc[2][r] + bi2 + rr_ * base[1024 + h]);
      const int o = b * HH + h;
      float v = (1.f - zz) * ng + zz * g_h1f[o];
      g_h1f[o] = v;
      hn[r] = v;
      const int off = (b >> 4) * 8192 + (h >> 5) * 512 + ((h >> 3) & 3) * 128 +
                      (b & 15) * 8 + (h & 7);
      unsigned short hi = bf16_rne(v);
      g_h1p[wb][off] = (short)hi;
      g_h1p[wb][131072 + off] = (short)bf16_rne(v - bf16_to_f(hi));
    }

    // transpose h1' (C-layout) -> A-fragment LDS for the logits MFMA
    const int kk = w * 16 + ci;  // block-local k (h col) 0..63
#pragma unroll
    for (int r = 0; r < 4; ++r) {
      const int m = qu * 4 + r;
      const int off = (kk >> 5) * 512 + ((kk >> 3) & 3) * 128 + m * 8 + (kk & 7);
      unsigned short hi = bf16_rne(hn[r]);
      Lh[off] = (short)hi;
      Ll[off] = (short)bf16_rne(hn[r] - bf16_to_f(hi));
    }
  }
  __syncthreads();

  // second GEMM: j-columns split across halves (j = half*4 + jj)
  f32x4 acc2[4] = {z, z, z, z};
#pragma unroll
  for (int S2 = 0; S2 < 2; ++S2) {
    bf16x8 ah = *(const bf16x8*)&Lh[S2 * 512 + lnoff];
    bf16x8 al = *(const bf16x8*)&Ll[S2 * 512 + lnoff];
#pragma unroll
    for (int jj = 0; jj < 4; ++jj) {
      const int nt = w * 8 + half * 4 + jj;
      const short* wp = g_Wout + (nt * 16 + nb * 2 + S2) * 512 + lnoff;
      bf16x8 bh = *(const bf16x8*)wp;
      bf16x8 bl = *(const bf16x8*)(wp + 262144);
      acc2[jj] = mfma16(ah, bh, acc2[jj]);
      acc2[jj] = mfma16(ah, bl, acc2[jj]);
      acc2[jj] = mfma16(al, bh, acc2[jj]);
    }
  }
  float* Ldst = g_logits[t & 1];
#pragma unroll
  for (int jj = 0; jj < 4; ++jj) {
    const int n = (w * 8 + half * 4 + jj) * 16 + ci;
#pragma unroll
    for (int r = 0; r < 4; ++r) {
      const int b = mt * 16 + qu * 4 + r;
      atomicAdd(&Ldst[b * NN + n], acc2[jj][r]);
    }
  }
}

// ---------------- host ----------------
extern "C" void kernel_launch(void* const* d_in, const int* in_sizes, int n_in,
                              void* d_out, int out_size, void* d_ws,
                              size_t ws_size, hipStream_t stream) {
  (void)in_sizes; (void)n_in; (void)d_ws; (void)ws_size;
  const float* W_ih0 = (const float*)d_in[1];
  const float* W_hh0 = (const float*)d_in[2];
  const float* b_ih0 = (const float*)d_in[3];
  const float* b_hh0 = (const float*)d_in[4];
  const float* W_ih1 = (const float*)d_in[5];
  const float* W_hh1 = (const float*)d_in[6];
  const float* b_ih1 = (const float*)d_in[7];
  const float* b_hh1 = (const float*)d_in[8];
  const float* W_out = (const float*)d_in[9];
  const float* b_out = (const float*)d_in[10];

  float* out = (float*)d_out;
  float* out_lp = out + (size_t)BB * NN * NN;

  hipMemsetAsync(d_out, 0, (size_t)out_size * sizeof(float), stream);
  init_state_kernel<<<1024, 256, 0, stream>>>();
  ones_row_kernel<<<6, 256, 0, stream>>>(W_ih0, b_ih0);
  transpose_kernel<<<dim3(16, 48), 256, 0, stream>>>(W_ih0);

  short* whh0; hipGetSymbolAddress((void**)&whh0, HIP_SYMBOL(g_Whh0));
  short* whh1; hipGetSymbolAddress((void**)&whh1, HIP_SYMBOL(g_Whh1));
  short* wih1; hipGetSymbolAddress((void**)&wih1, HIP_SYMBOL(g_Wih1));
  short* wout; hipGetSymbolAddress((void**)&wout, HIP_SYMBOL(g_Wout));
  split_kernel<<<384, 256, 0, stream>>>(W_hh0, whh0, G3, 786432);
  split_kernel<<<384, 256, 0, stream>>>(W_hh1, whh1, G3, 786432);
  split_kernel<<<384, 256, 0, stream>>>(W_ih1, wih1, G3, 786432);
  split_kernel<<<128, 256, 0, stream>>>(W_out, wout, NN, 262144);

  for (int t = 0; t < NN; ++t) {
    k1_layer0<<<256, 512, 0, stream>>>(t, b_ih0, b_hh0, b_hh1, b_out, out,
                                       out_lp);
    k2_layer1<<<128, 512, 0, stream>>>(t, b_ih1);
  }
  // tail: replay and finalize step 511
  k0_sample<<<16, 256, 0, stream>>>(NN, b_out, out, out_lp);
}